// Round 5
// baseline (719.582 us; speedup 1.0000x reference)
//
#include <hip/hip_runtime.h>
#include <stdint.h>

#define B_ 8
#define T_ 128
#define N_ 64
#define D_ 1024
#define H_ 512

typedef __attribute__((ext_vector_type(8))) short bf16x8;
typedef __attribute__((ext_vector_type(4))) float f32x4;

__device__ __forceinline__ unsigned short f2bf(float x) {
  union { float f; unsigned u; } c; c.f = x;
  unsigned r = c.u + 0x7FFFu + ((c.u >> 16) & 1u);
  return (unsigned short)(r >> 16);
}

// ---------------- K0a: transpose U_weight [H,D] -> Ut [D,H] ----------------
__global__ __launch_bounds__(256) void k_transU(const float* __restrict__ U,
                                                float* __restrict__ Ut) {
  __shared__ float tile[32][33];
  int d0 = blockIdx.x * 32, h0 = blockIdx.y * 32;
  int lx = threadIdx.x & 31, ly = threadIdx.x >> 5;  // ly: 0..7
#pragma unroll
  for (int i = 0; i < 32; i += 8)
    tile[ly + i][lx] = U[(size_t)(h0 + ly + i) * D_ + d0 + lx];
  __syncthreads();
#pragma unroll
  for (int i = 0; i < 32; i += 8)
    Ut[(size_t)(d0 + ly + i) * H_ + h0 + lx] = tile[lx][ly + i];
}

// ---- K0b: W [H,D] fp32 -> Wt bf16, k-tiled + XOR-pre-swizzled -------------
// Wt element i: e=i&7, cs=(i>>3)&3, h=(i>>5)&511, kt=i>>14
// holds W[h][kt*32 + ((cs^(h&3))<<3 | e)]
__global__ __launch_bounds__(512) void k_convW(const float* __restrict__ W,
                                               unsigned short* __restrict__ Wt) {
  int i = blockIdx.x * 512 + threadIdx.x;  // 0..524287
  int e = i & 7, cs = (i >> 3) & 3, h = (i >> 5) & 511, kt = i >> 14;
  int k = kt * 32 + (((cs ^ (h & 3)) << 3) | e);
  Wt[i] = f2bf(W[(size_t)h * D_ + k]);
}

// ---- K1: Uhb[b][n][h] = hidden[n][b][:] . Ut[:,h] + U_bias[h] + W_bias[h] -
__global__ __launch_bounds__(512) void k_uh(const float* __restrict__ hidden,
                                            const float* __restrict__ Ut,
                                            const float* __restrict__ Ub,
                                            const float* __restrict__ Wb,
                                            float* __restrict__ Uhb) {
  __shared__ float xs[8][1024];
  int b = blockIdx.x >> 3, ng = blockIdx.x & 7, tid = threadIdx.x;
  for (int i = tid; i < 8192; i += 512) {
    int nn = i >> 10, d = i & 1023;
    xs[nn][d] = hidden[(size_t)((ng * 8 + nn) * B_ + b) * D_ + d];
  }
  __syncthreads();
  float acc[8];
#pragma unroll
  for (int nn = 0; nn < 8; ++nn) acc[nn] = 0.f;
  for (int d = 0; d < 1024; ++d) {
    float u = Ut[(size_t)d * H_ + tid];
#pragma unroll
    for (int nn = 0; nn < 8; ++nn) acc[nn] += xs[nn][d] * u;
  }
  float bias = Ub[tid] + Wb[tid];
#pragma unroll
  for (int nn = 0; nn < 8; ++nn)
    Uhb[(size_t)(b * 64 + ng * 8 + nn) * H_ + tid] = acc[nn] + bias;
}

// ---- K2: fused  e = sum_h tanh(img@W^T + Uhb)*w ; softmax_n -> alpha ------
// one block per (b,t): 64 rows (n) x 512 cols (h), K=1024, BK=32
// 8 waves: wave w -> (wm=w>>2) 32 rows x (wn=w&3) 128 cols; 2x8 16x16 frags
__global__ __launch_bounds__(512, 2) void k_main(const float* __restrict__ img,
                                                 const unsigned short* __restrict__ Wt,
                                                 const float* __restrict__ Uhb,
                                                 const float* __restrict__ ww,
                                                 const float* __restrict__ wb,
                                                 float* __restrict__ alpha) {
  __shared__ __align__(16) unsigned char sA[4096];    // 64 rows x 32 bf16
  __shared__ __align__(16) unsigned char sB[32768];   // 512 rows x 32 bf16
  __shared__ float e_part[256];                       // [64 rows][4 wn]
  const int tid = threadIdx.x;
  const int bt = blockIdx.x;
  const int b = bt >> 7;
  const int lane = tid & 63, w = tid >> 6, wm = w >> 2, wn = w & 3;
  const int lo = lane & 15, hi = lane >> 4;

  // A staging: thread -> one float4 of img per k-step
  const int rowA = tid >> 3, c4 = tid & 7;
  const float* gA = img + (size_t)bt * 65536 + rowA * 1024 + c4 * 4;
  const int sAoff = rowA * 64 + ((((c4 >> 1) ^ (rowA & 3)) << 4) | ((c4 & 1) << 3));
  // B staging: linear copy of pre-swizzled 32KB tile
  const uint4* gB = (const uint4*)Wt;

  // fragment read offsets (swizzle matches the stored layout)
  const int swz = ((hi ^ (lane & 3)) << 4);
  const int base_a = (wm * 32 + lo) * 64 + swz;
  const int base_b = (wn * 128 + lo) * 64 + swz;

  f32x4 acc[2][8] = {};

  for (int kt = 0; kt < 32; ++kt) {
    float4 av = *(const float4*)(gA + kt * 32);
    uint4 b0 = gB[kt * 2048 + 0 * 512 + tid];
    uint4 b1 = gB[kt * 2048 + 1 * 512 + tid];
    uint4 b2 = gB[kt * 2048 + 2 * 512 + tid];
    uint4 b3 = gB[kt * 2048 + 3 * 512 + tid];
    uint2 pk;
    pk.x = (unsigned)f2bf(av.x) | ((unsigned)f2bf(av.y) << 16);
    pk.y = (unsigned)f2bf(av.z) | ((unsigned)f2bf(av.w) << 16);
    *(uint2*)(sA + sAoff) = pk;
    *(uint4*)(sB + (0 * 512 + tid) * 16) = b0;
    *(uint4*)(sB + (1 * 512 + tid) * 16) = b1;
    *(uint4*)(sB + (2 * 512 + tid) * 16) = b2;
    *(uint4*)(sB + (3 * 512 + tid) * 16) = b3;
    __syncthreads();

    bf16x8 aF0 = *(const bf16x8*)(sA + base_a);
    bf16x8 aF1 = *(const bf16x8*)(sA + base_a + 1024);
    bf16x8 bF[8];
#pragma unroll
    for (int nf = 0; nf < 8; ++nf) bF[nf] = *(const bf16x8*)(sB + base_b + nf * 1024);
#pragma unroll
    for (int nf = 0; nf < 8; ++nf) {
      acc[0][nf] = __builtin_amdgcn_mfma_f32_16x16x32_bf16(aF0, bF[nf], acc[0][nf], 0, 0, 0);
      acc[1][nf] = __builtin_amdgcn_mfma_f32_16x16x32_bf16(aF1, bF[nf], acc[1][nf], 0, 0, 0);
    }
    __syncthreads();
  }

  // epilogue: e partial per lane; C frag: row=(hi*4+r), col=lo
  float ep[2][4] = {{0.f, 0.f, 0.f, 0.f}, {0.f, 0.f, 0.f, 0.f}};
  const float* Ubase = Uhb + (size_t)b * 64 * 512;
#pragma unroll
  for (int mf = 0; mf < 2; ++mf) {
#pragma unroll
    for (int r = 0; r < 4; ++r) {
      const int row = wm * 32 + mf * 16 + hi * 4 + r;
      const float* urow = Ubase + (size_t)row * 512;
      float s = 0.f;
#pragma unroll
      for (int nf = 0; nf < 8; ++nf) {
        const int h = wn * 128 + nf * 16 + lo;
        float v = acc[mf][nf][r] + urow[h];
        s += tanhf(v) * ww[h];
      }
      ep[mf][r] = s;
    }
  }
#pragma unroll
  for (int mf = 0; mf < 2; ++mf) {
#pragma unroll
    for (int r = 0; r < 4; ++r) {
      float v = ep[mf][r];
      v += __shfl_xor(v, 1);
      v += __shfl_xor(v, 2);
      v += __shfl_xor(v, 4);
      v += __shfl_xor(v, 8);
      if (lo == 0) e_part[(wm * 32 + mf * 16 + hi * 4 + r) * 4 + wn] = v;
    }
  }
  __syncthreads();
  if (tid < 64) {
    float e = e_part[tid * 4] + e_part[tid * 4 + 1] + e_part[tid * 4 + 2] +
              e_part[tid * 4 + 3] + wb[0];
    float m = e;
#pragma unroll
    for (int s = 32; s; s >>= 1) m = fmaxf(m, __shfl_xor(m, s));
    float p = expf(e - m);
    float su = p;
#pragma unroll
    for (int s = 32; s; s >>= 1) su += __shfl_xor(su, s);
    alpha[bt * 64 + tid] = p / su;
  }
}

// ---- K3: phi[b,t,d] = sum_n alpha[b,t,n] * img[b,t,n,d] -------------------
__global__ __launch_bounds__(256) void k_phi(const float* __restrict__ img,
                                             const float* __restrict__ alpha,
                                             float* __restrict__ out) {
  __shared__ float alf[64];
  int bt = blockIdx.x, tid = threadIdx.x;
  if (tid < 64) alf[tid] = alpha[bt * 64 + tid];
  __syncthreads();
  const float4* ip = (const float4*)img + (size_t)bt * 16384 + tid;
  float4 s = make_float4(0.f, 0.f, 0.f, 0.f);
#pragma unroll 8
  for (int n = 0; n < 64; ++n) {
    float a = alf[n];
    float4 v = ip[(size_t)n * 256];
    s.x += a * v.x; s.y += a * v.y; s.z += a * v.z; s.w += a * v.w;
  }
  ((float4*)out)[(size_t)bt * 256 + tid] = s;
}

extern "C" void kernel_launch(void* const* d_in, const int* in_sizes, int n_in,
                              void* d_out, int out_size, void* d_ws, size_t ws_size,
                              hipStream_t stream) {
  const float* img    = (const float*)d_in[0];
  const float* hidden = (const float*)d_in[1];
  const float* Ww     = (const float*)d_in[2];
  const float* Wb     = (const float*)d_in[3];
  const float* Uw     = (const float*)d_in[4];
  const float* Ub     = (const float*)d_in[5];
  const float* ww     = (const float*)d_in[6];
  const float* wb     = (const float*)d_in[7];
  float* out = (float*)d_out;
  char* ws = (char*)d_ws;

  // ws layout (4 MB total):
  //   [0, 2MB)   Ut (fp32 [D,H])    -- dead after K1; alpha reuses offset 0
  //   [2MB, 3MB) Wt (bf16, tiled+swizzled)
  //   [3MB, 4MB) Uhb (fp32 [B,N,H], biases folded)
  float* Ut            = (float*)ws;
  unsigned short* Wt   = (unsigned short*)(ws + (2u << 20));
  float* Uhb           = (float*)(ws + (3u << 20));
  float* alpha         = (float*)ws;  // overlaps Ut (Ut consumed before K2)

  k_transU<<<dim3(32, 16), 256, 0, stream>>>(Uw, Ut);
  k_convW<<<1024, 512, 0, stream>>>(Ww, Wt);
  k_uh<<<64, 512, 0, stream>>>(hidden, Ut, Ub, Wb, Uhb);
  k_main<<<1024, 512, 0, stream>>>(img, Wt, Uhb, ww, wb, alpha);
  k_phi<<<1024, 256, 0, stream>>>(img, alpha, out);
}

// Round 6
// 598.346 us; speedup vs baseline: 1.2026x; 1.2026x over previous
//
#include <hip/hip_runtime.h>
#include <stdint.h>

#define B_ 8
#define T_ 128
#define N_ 64
#define D_ 1024
#define H_ 512

typedef __attribute__((ext_vector_type(8))) short bf16x8;
typedef __attribute__((ext_vector_type(4))) float f32x4;

__device__ __forceinline__ unsigned short f2bf(float x) {
  union { float f; unsigned u; } c; c.f = x;
  unsigned r = c.u + 0x7FFFu + ((c.u >> 16) & 1u);
  return (unsigned short)(r >> 16);
}

// ---------------- K0a: transpose U_weight [H,D] -> Ut [D,H] ----------------
__global__ __launch_bounds__(256) void k_transU(const float* __restrict__ U,
                                                float* __restrict__ Ut) {
  __shared__ float tile[32][33];
  int d0 = blockIdx.x * 32, h0 = blockIdx.y * 32;
  int lx = threadIdx.x & 31, ly = threadIdx.x >> 5;  // ly: 0..7
#pragma unroll
  for (int i = 0; i < 32; i += 8)
    tile[ly + i][lx] = U[(size_t)(h0 + ly + i) * D_ + d0 + lx];
  __syncthreads();
#pragma unroll
  for (int i = 0; i < 32; i += 8)
    Ut[(size_t)(d0 + ly + i) * H_ + h0 + lx] = tile[lx][ly + i];
}

// ---- K0b: W [H,D] fp32 -> Wt bf16, k-tiled + XOR-pre-swizzled -------------
// Wt element i: e=i&7, cs=(i>>3)&3, h=(i>>5)&511, kt=i>>14
// holds W[h][kt*32 + ((cs^(h&3))<<3 | e)]
__global__ __launch_bounds__(512) void k_convW(const float* __restrict__ W,
                                               unsigned short* __restrict__ Wt) {
  int i = blockIdx.x * 512 + threadIdx.x;  // 0..524287
  int e = i & 7, cs = (i >> 3) & 3, h = (i >> 5) & 511, kt = i >> 14;
  int k = kt * 32 + (((cs ^ (h & 3)) << 3) | e);
  Wt[i] = f2bf(W[(size_t)h * D_ + k]);
}

// ---- K1: Uhb[b][n][h] = hidden[n][b][:] . Ut[:,h] + U_bias[h] + W_bias[h] -
__global__ __launch_bounds__(512) void k_uh(const float* __restrict__ hidden,
                                            const float* __restrict__ Ut,
                                            const float* __restrict__ Ub,
                                            const float* __restrict__ Wb,
                                            float* __restrict__ Uhb) {
  __shared__ float xs[8][1024];
  int b = blockIdx.x >> 3, ng = blockIdx.x & 7, tid = threadIdx.x;
  for (int i = tid; i < 8192; i += 512) {
    int nn = i >> 10, d = i & 1023;
    xs[nn][d] = hidden[(size_t)((ng * 8 + nn) * B_ + b) * D_ + d];
  }
  __syncthreads();
  float acc[8];
#pragma unroll
  for (int nn = 0; nn < 8; ++nn) acc[nn] = 0.f;
  // 8-way unrolled d-loop: 8 independent Ut loads in flight per thread
  for (int d0 = 0; d0 < 1024; d0 += 8) {
    float u[8];
#pragma unroll
    for (int j = 0; j < 8; ++j) u[j] = Ut[(size_t)(d0 + j) * H_ + tid];
#pragma unroll
    for (int j = 0; j < 8; ++j) {
#pragma unroll
      for (int nn = 0; nn < 8; ++nn) acc[nn] += xs[nn][d0 + j] * u[j];
    }
  }
  float bias = Ub[tid] + Wb[tid];
#pragma unroll
  for (int nn = 0; nn < 8; ++nn)
    Uhb[(size_t)(b * 64 + ng * 8 + nn) * H_ + tid] = acc[nn] + bias;
}

// ---- K2: fused  e = sum_h tanh(img@W^T + Uhb)*w ; softmax_n -> alpha ------
// one block per (b,t): 64 rows (n) x 512 cols (h), K=1024, BK=32
// 8 waves: wave w -> (wm=w>>2) 32 rows x (wn=w&3) 128 cols; 2x8 16x16 frags
// Double-buffered LDS + register prefetch: ONE barrier per K-step.
//   iter kt: issue loads(kt+1)->regs | ds_read+MFMA on buf[cur] |
//            vmcnt + ds_write regs->buf[cur^1] | barrier
//   (write of buf[cur^1] vs iter kt-1's reads of it: separated by kt-1's
//    barrier; reads of buf[cur] are concurrent with writes of buf[cur^1] —
//    disjoint buffers, race-free.)
__global__ __launch_bounds__(512, 4) void k_main(const float* __restrict__ img,
                                                 const unsigned short* __restrict__ Wt,
                                                 const float* __restrict__ Uhb,
                                                 const float* __restrict__ ww,
                                                 const float* __restrict__ wb,
                                                 float* __restrict__ alpha) {
  __shared__ __align__(16) unsigned char sA[2][4096];    // 64 rows x 32 bf16
  __shared__ __align__(16) unsigned char sB[2][32768];   // 512 rows x 32 bf16
  __shared__ float e_part[256];                          // [64 rows][4 wn]
  const int tid = threadIdx.x;
  const int bt = blockIdx.x;
  const int b = bt >> 7;
  const int lane = tid & 63, w = tid >> 6, wm = w >> 2, wn = w & 3;
  const int lo = lane & 15, hi = lane >> 4;

  // A staging: thread -> one float4 of img per k-step
  const int rowA = tid >> 3, c4 = tid & 7;
  const float* gA = img + (size_t)bt * 65536 + rowA * 1024 + c4 * 4;
  const int sAoff = rowA * 64 + ((((c4 >> 1) ^ (rowA & 3)) << 4) | ((c4 & 1) << 3));
  // B staging: linear copy of pre-swizzled 32KB tile
  const uint4* gB = (const uint4*)Wt;

  // fragment read offsets (swizzle matches the stored layout)
  const int swz = ((hi ^ (lane & 3)) << 4);
  const int base_a = (wm * 32 + lo) * 64 + swz;
  const int base_b = (wn * 128 + lo) * 64 + swz;

  f32x4 acc[2][8] = {};

  // ---- prologue: stage kt=0 into buffer 0 ----
  {
    float4 av = *(const float4*)(gA);
    uint4 b0 = gB[0 * 512 + tid];
    uint4 b1 = gB[1 * 512 + tid];
    uint4 b2 = gB[2 * 512 + tid];
    uint4 b3 = gB[3 * 512 + tid];
    uint2 pk;
    pk.x = (unsigned)f2bf(av.x) | ((unsigned)f2bf(av.y) << 16);
    pk.y = (unsigned)f2bf(av.z) | ((unsigned)f2bf(av.w) << 16);
    *(uint2*)(sA[0] + sAoff) = pk;
    *(uint4*)(sB[0] + (0 * 512 + tid) * 16) = b0;
    *(uint4*)(sB[0] + (1 * 512 + tid) * 16) = b1;
    *(uint4*)(sB[0] + (2 * 512 + tid) * 16) = b2;
    *(uint4*)(sB[0] + (3 * 512 + tid) * 16) = b3;
  }
  __syncthreads();

  for (int kt = 0; kt < 32; ++kt) {
    const int cur = kt & 1;
    // ---- issue prefetch of kt+1 into registers (flies under the MFMAs) ----
    float4 av;
    uint4 nb0, nb1, nb2, nb3;
    if (kt < 31) {
      av = *(const float4*)(gA + (kt + 1) * 32);
      const uint4* gBk = gB + (size_t)(kt + 1) * 2048;
      nb0 = gBk[0 * 512 + tid];
      nb1 = gBk[1 * 512 + tid];
      nb2 = gBk[2 * 512 + tid];
      nb3 = gBk[3 * 512 + tid];
    }

    // ---- compute on buf[cur] ----
    const unsigned char* cA = sA[cur];
    const unsigned char* cB = sB[cur];
    bf16x8 aF0 = *(const bf16x8*)(cA + base_a);
    bf16x8 aF1 = *(const bf16x8*)(cA + base_a + 1024);
    {
      bf16x8 bF0 = *(const bf16x8*)(cB + base_b + 0 * 1024);
      bf16x8 bF1 = *(const bf16x8*)(cB + base_b + 1 * 1024);
      bf16x8 bF2 = *(const bf16x8*)(cB + base_b + 2 * 1024);
      bf16x8 bF3 = *(const bf16x8*)(cB + base_b + 3 * 1024);
      acc[0][0] = __builtin_amdgcn_mfma_f32_16x16x32_bf16(aF0, bF0, acc[0][0], 0, 0, 0);
      acc[1][0] = __builtin_amdgcn_mfma_f32_16x16x32_bf16(aF1, bF0, acc[1][0], 0, 0, 0);
      acc[0][1] = __builtin_amdgcn_mfma_f32_16x16x32_bf16(aF0, bF1, acc[0][1], 0, 0, 0);
      acc[1][1] = __builtin_amdgcn_mfma_f32_16x16x32_bf16(aF1, bF1, acc[1][1], 0, 0, 0);
      acc[0][2] = __builtin_amdgcn_mfma_f32_16x16x32_bf16(aF0, bF2, acc[0][2], 0, 0, 0);
      acc[1][2] = __builtin_amdgcn_mfma_f32_16x16x32_bf16(aF1, bF2, acc[1][2], 0, 0, 0);
      acc[0][3] = __builtin_amdgcn_mfma_f32_16x16x32_bf16(aF0, bF3, acc[0][3], 0, 0, 0);
      acc[1][3] = __builtin_amdgcn_mfma_f32_16x16x32_bf16(aF1, bF3, acc[1][3], 0, 0, 0);
    }
    {
      bf16x8 bF4 = *(const bf16x8*)(cB + base_b + 4 * 1024);
      bf16x8 bF5 = *(const bf16x8*)(cB + base_b + 5 * 1024);
      bf16x8 bF6 = *(const bf16x8*)(cB + base_b + 6 * 1024);
      bf16x8 bF7 = *(const bf16x8*)(cB + base_b + 7 * 1024);
      acc[0][4] = __builtin_amdgcn_mfma_f32_16x16x32_bf16(aF0, bF4, acc[0][4], 0, 0, 0);
      acc[1][4] = __builtin_amdgcn_mfma_f32_16x16x32_bf16(aF1, bF4, acc[1][4], 0, 0, 0);
      acc[0][5] = __builtin_amdgcn_mfma_f32_16x16x32_bf16(aF0, bF5, acc[0][5], 0, 0, 0);
      acc[1][5] = __builtin_amdgcn_mfma_f32_16x16x32_bf16(aF1, bF5, acc[1][5], 0, 0, 0);
      acc[0][6] = __builtin_amdgcn_mfma_f32_16x16x32_bf16(aF0, bF6, acc[0][6], 0, 0, 0);
      acc[1][6] = __builtin_amdgcn_mfma_f32_16x16x32_bf16(aF1, bF6, acc[1][6], 0, 0, 0);
      acc[0][7] = __builtin_amdgcn_mfma_f32_16x16x32_bf16(aF0, bF7, acc[0][7], 0, 0, 0);
      acc[1][7] = __builtin_amdgcn_mfma_f32_16x16x32_bf16(aF1, bF7, acc[1][7], 0, 0, 0);
    }

    // ---- stage kt+1 into the other buffer (vmcnt waits land here) ----
    if (kt < 31) {
      const int nxt = cur ^ 1;
      uint2 pk;
      pk.x = (unsigned)f2bf(av.x) | ((unsigned)f2bf(av.y) << 16);
      pk.y = (unsigned)f2bf(av.z) | ((unsigned)f2bf(av.w) << 16);
      *(uint2*)(sA[nxt] + sAoff) = pk;
      *(uint4*)(sB[nxt] + (0 * 512 + tid) * 16) = nb0;
      *(uint4*)(sB[nxt] + (1 * 512 + tid) * 16) = nb1;
      *(uint4*)(sB[nxt] + (2 * 512 + tid) * 16) = nb2;
      *(uint4*)(sB[nxt] + (3 * 512 + tid) * 16) = nb3;
    }
    __syncthreads();
  }

  // epilogue: e partial per lane; C frag: row=(hi*4+r), col=lo
  float ep[2][4] = {{0.f, 0.f, 0.f, 0.f}, {0.f, 0.f, 0.f, 0.f}};
  const float* Ubase = Uhb + (size_t)b * 64 * 512;
#pragma unroll
  for (int mf = 0; mf < 2; ++mf) {
#pragma unroll
    for (int r = 0; r < 4; ++r) {
      const int row = wm * 32 + mf * 16 + hi * 4 + r;
      const float* urow = Ubase + (size_t)row * 512;
      float s = 0.f;
#pragma unroll
      for (int nf = 0; nf < 8; ++nf) {
        const int h = wn * 128 + nf * 16 + lo;
        float v = acc[mf][nf][r] + urow[h];
        s += tanhf(v) * ww[h];
      }
      ep[mf][r] = s;
    }
  }
#pragma unroll
  for (int mf = 0; mf < 2; ++mf) {
#pragma unroll
    for (int r = 0; r < 4; ++r) {
      float v = ep[mf][r];
      v += __shfl_xor(v, 1);
      v += __shfl_xor(v, 2);
      v += __shfl_xor(v, 4);
      v += __shfl_xor(v, 8);
      if (lo == 0) e_part[(wm * 32 + mf * 16 + hi * 4 + r) * 4 + wn] = v;
    }
  }
  __syncthreads();
  if (tid < 64) {
    float e = e_part[tid * 4] + e_part[tid * 4 + 1] + e_part[tid * 4 + 2] +
              e_part[tid * 4 + 3] + wb[0];
    float m = e;
#pragma unroll
    for (int s = 32; s; s >>= 1) m = fmaxf(m, __shfl_xor(m, s));
    float p = expf(e - m);
    float su = p;
#pragma unroll
    for (int s = 32; s; s >>= 1) su += __shfl_xor(su, s);
    alpha[bt * 64 + tid] = p / su;
  }
}

// ---- K3: phi[b,t,d] = sum_n alpha[b,t,n] * img[b,t,n,d] -------------------
__global__ __launch_bounds__(256) void k_phi(const float* __restrict__ img,
                                             const float* __restrict__ alpha,
                                             float* __restrict__ out) {
  __shared__ float alf[64];
  int bt = blockIdx.x, tid = threadIdx.x;
  if (tid < 64) alf[tid] = alpha[bt * 64 + tid];
  __syncthreads();
  const float4* ip = (const float4*)img + (size_t)bt * 16384 + tid;
  float4 s = make_float4(0.f, 0.f, 0.f, 0.f);
#pragma unroll 8
  for (int n = 0; n < 64; ++n) {
    float a = alf[n];
    float4 v = ip[(size_t)n * 256];
    s.x += a * v.x; s.y += a * v.y; s.z += a * v.z; s.w += a * v.w;
  }
  ((float4*)out)[(size_t)bt * 256 + tid] = s;
}

extern "C" void kernel_launch(void* const* d_in, const int* in_sizes, int n_in,
                              void* d_out, int out_size, void* d_ws, size_t ws_size,
                              hipStream_t stream) {
  const float* img    = (const float*)d_in[0];
  const float* hidden = (const float*)d_in[1];
  const float* Ww     = (const float*)d_in[2];
  const float* Wb     = (const float*)d_in[3];
  const float* Uw     = (const float*)d_in[4];
  const float* Ub     = (const float*)d_in[5];
  const float* ww     = (const float*)d_in[6];
  const float* wb     = (const float*)d_in[7];
  float* out = (float*)d_out;
  char* ws = (char*)d_ws;

  // ws layout (4 MB total):
  //   [0, 2MB)   Ut (fp32 [D,H])    -- dead after K1; alpha reuses offset 0
  //   [2MB, 3MB) Wt (bf16, tiled+swizzled)
  //   [3MB, 4MB) Uhb (fp32 [B,N,H], biases folded)
  float* Ut            = (float*)ws;
  unsigned short* Wt   = (unsigned short*)(ws + (2u << 20));
  float* Uhb           = (float*)(ws + (3u << 20));
  float* alpha         = (float*)ws;  // overlaps Ut (Ut consumed before K2)

  k_transU<<<dim3(32, 16), 256, 0, stream>>>(Uw, Ut);
  k_convW<<<1024, 512, 0, stream>>>(Ww, Wt);
  k_uh<<<64, 512, 0, stream>>>(hidden, Ut, Ub, Wb, Uhb);
  k_main<<<1024, 512, 0, stream>>>(img, Wt, Uhb, ww, wb, alpha);
  k_phi<<<1024, 256, 0, stream>>>(img, alpha, out);
}